// Round 1
// baseline (2057.935 us; speedup 1.0000x reference)
//
#include <hip/hip_runtime.h>
#include <math.h>

#define Tn 64
#define Bn 32
#define Pn 9
#define Dn 512
#define TBn 2048
#define G3 1536

__device__ __forceinline__ float fsigmoid(float x){ return 1.0f/(1.0f+__expf(-x)); }

// ---------- prep: qi/qni argmax, zero h0, zero out row 0, zero counts ----------
__global__ void k_prep(const float* __restrict__ qmask, int* __restrict__ qi,
                       int* __restrict__ qni, float* __restrict__ h0,
                       float* __restrict__ out, int* __restrict__ counts){
  int t = blockIdx.x; int tid = threadIdx.x;
  if (blockIdx.x == 0 && tid < 16) counts[tid] = 0;
  if (tid < Bn){
    int b = tid;
    const float* qm = qmask + ((size_t)t*Bn + b)*Pn;
    int best = 0; float bv = qm[0];
    #pragma unroll
    for (int p=1;p<Pn;p++){ float v=qm[p]; if (v>bv){bv=v;best=p;} }
    qi[t*Bn+b] = best;
    int tn = (t==Tn-1)? t : t+1;
    const float* qmn = qmask + ((size_t)tn*Bn + b)*Pn;
    best = 0; bv = qmn[0];
    #pragma unroll
    for (int p=1;p<Pn;p++){ float v=qmn[p]; if (v>bv){bv=v;best=p;} }
    qni[t*Bn+b] = best;
  }
  for (int i=tid; i<2304; i+=256) h0[t*2304 + i] = 0.f;       // 64*2304 = 32*9*512
  for (int i=tid; i<256;  i+=256) out[t*256 + i] = 0.f;       // 64*256 = 32*512 (row 0)
}

// ---------- build per-party sample lists for the gi gather-GEMM ----------
__global__ void k_lists(const int* __restrict__ qi, const int* __restrict__ qni,
                        int* __restrict__ counts, int* __restrict__ lists){
  int id = blockIdx.x*256 + threadIdx.x;   // 0..4095 ; id = role*2048 + t*32+b
  int role = id >> 11, tb = id & (TBn-1);
  int p = role ? qni[tb] : qi[tb];
  int slot = atomicAdd(&counts[p], 1);
  lists[p*4096 + slot] = id;
}

// ---------- generic f32 GEMM: C[M,N] = A[M,512] @ W[N,512]^T + bias ----------
#define BM 64
#define BN 64
#define BK 32
__global__ __launch_bounds__(256) void k_gemm(const float* __restrict__ A, int lda,
      const float* __restrict__ W, const float* __restrict__ bias,
      float* __restrict__ C, int N){
  __shared__ float As[BM][BK+1];
  __shared__ float Ws[BN][BK+1];
  int bm = blockIdx.y*BM, bn = blockIdx.x*BN;
  int tid = threadIdx.x;
  int tx = tid & 15, ty = tid >> 4;
  int r = tid >> 2, kc = (tid & 3)*8;
  float acc[4][4] = {};
  for (int k0=0; k0<Dn; k0+=BK){
    float4 a0 = *(const float4*)(A + (size_t)(bm+r)*lda + k0 + kc);
    float4 a1 = *(const float4*)(A + (size_t)(bm+r)*lda + k0 + kc + 4);
    float4 w0 = *(const float4*)(W + (size_t)(bn+r)*Dn + k0 + kc);
    float4 w1 = *(const float4*)(W + (size_t)(bn+r)*Dn + k0 + kc + 4);
    __syncthreads();
    As[r][kc+0]=a0.x; As[r][kc+1]=a0.y; As[r][kc+2]=a0.z; As[r][kc+3]=a0.w;
    As[r][kc+4]=a1.x; As[r][kc+5]=a1.y; As[r][kc+6]=a1.z; As[r][kc+7]=a1.w;
    Ws[r][kc+0]=w0.x; Ws[r][kc+1]=w0.y; Ws[r][kc+2]=w0.z; Ws[r][kc+3]=w0.w;
    Ws[r][kc+4]=w1.x; Ws[r][kc+5]=w1.y; Ws[r][kc+6]=w1.z; Ws[r][kc+7]=w1.w;
    __syncthreads();
    #pragma unroll
    for (int kk=0; kk<BK; kk++){
      float a[4], w[4];
      #pragma unroll
      for (int i=0;i<4;i++) a[i] = As[ty*4+i][kk];
      #pragma unroll
      for (int j=0;j<4;j++) w[j] = Ws[tx*4+j][kk];
      #pragma unroll
      for (int i=0;i<4;i++)
        #pragma unroll
        for (int j=0;j<4;j++) acc[i][j] = fmaf(a[i], w[j], acc[i][j]);
    }
  }
  #pragma unroll
  for (int i=0;i<4;i++){
    int row = bm + ty*4 + i;
    #pragma unroll
    for (int j=0;j<4;j++){
      int col = bn + tx*4 + j;
      float v = acc[i][j];
      if (bias) v += bias[col];
      C[(size_t)row*N + col] = v;
    }
  }
}

// ---------- per-t batch-axis softmax + context scale:  s = score_b * pkx + bp ----------
__global__ __launch_bounds__(256) void k_score(const float* __restrict__ qx,
      const float* __restrict__ kx, int kstride,
      const float* __restrict__ pkx, const float* __restrict__ bp,
      float* __restrict__ sout){
  int t = blockIdx.x; int tid = threadIdx.x;
  __shared__ float part[256];
  __shared__ float dots[32];
  __shared__ float sc[32];
  int b = tid >> 3, j = tid & 7;
  const float* q = qx + ((size_t)t*Bn + b)*Dn;
  const float* k = kx + ((size_t)t*Bn + b)*kstride;
  float s = 0.f;
  for (int d=j; d<Dn; d+=8) s = fmaf(q[d], k[d], s);
  part[tid] = s;
  __syncthreads();
  if (tid < 32){
    float acc = 0.f;
    #pragma unroll
    for (int jj=0;jj<8;jj++) acc += part[tid*8+jj];
    dots[tid] = acc;
  }
  __syncthreads();
  if (tid < 32){
    float mx = dots[0];
    for (int o=1;o<32;o++) mx = fmaxf(mx, dots[o]);
    sc[tid] = __expf(dots[tid] - mx);
  }
  __syncthreads();
  float myscore = 0.f;
  if (tid < 32){
    float sum = 0.f;
    for (int o=0;o<32;o++) sum += sc[o];
    myscore = sc[tid] / sum;
  }
  __syncthreads();
  if (tid < 32) sc[tid] = myscore;
  __syncthreads();
  for (int idx=tid; idx<Bn*Dn; idx+=256){
    int bb = idx >> 9, d = idx & (Dn-1);
    size_t o = ((size_t)t*Bn+bb)*Dn + d;
    sout[o] = fmaf(sc[bb], pkx[o], bp[d]);
  }
}

// ---------- gi gather-GEMM per party:  gi[row] = Wih[p] @ x_row + bih[p] ----------
__global__ __launch_bounds__(256) void k_gi(const float* __restrict__ ss,
      const float* __restrict__ sl, const float* __restrict__ Wih,
      const float* __restrict__ bih, const int* __restrict__ counts,
      const int* __restrict__ lists, float* __restrict__ gis, float* __restrict__ gil){
  int p = blockIdx.z;
  int cnt = counts[p];
  int mt = blockIdx.y;
  if (mt*BM >= cnt) return;
  int nt = blockIdx.x;
  __shared__ float As[BM][BK+1];
  __shared__ float Ws[BN][BK+1];
  __shared__ int rid[BM];
  int tid = threadIdx.x;
  if (tid < BM){
    int m = mt*BM + tid;
    rid[tid] = (m < cnt) ? lists[p*4096 + m] : -1;
  }
  __syncthreads();
  int tx = tid & 15, ty = tid >> 4;
  int r = tid >> 2, kc = (tid & 3)*8;
  int id = rid[r];
  const float* Asrc = nullptr;
  if (id >= 0) Asrc = ((id >> 11) ? sl : ss) + (size_t)(id & (TBn-1))*Dn;
  const float* Wsrc = Wih + ((size_t)p*G3 + (size_t)nt*BN)*Dn;
  float acc[4][4] = {};
  for (int k0=0; k0<Dn; k0+=BK){
    float4 a0 = {0,0,0,0}, a1 = {0,0,0,0};
    if (Asrc){
      a0 = *(const float4*)(Asrc + k0 + kc);
      a1 = *(const float4*)(Asrc + k0 + kc + 4);
    }
    float4 w0 = *(const float4*)(Wsrc + (size_t)r*Dn + k0 + kc);
    float4 w1 = *(const float4*)(Wsrc + (size_t)r*Dn + k0 + kc + 4);
    __syncthreads();
    As[r][kc+0]=a0.x; As[r][kc+1]=a0.y; As[r][kc+2]=a0.z; As[r][kc+3]=a0.w;
    As[r][kc+4]=a1.x; As[r][kc+5]=a1.y; As[r][kc+6]=a1.z; As[r][kc+7]=a1.w;
    Ws[r][kc+0]=w0.x; Ws[r][kc+1]=w0.y; Ws[r][kc+2]=w0.z; Ws[r][kc+3]=w0.w;
    Ws[r][kc+4]=w1.x; Ws[r][kc+5]=w1.y; Ws[r][kc+6]=w1.z; Ws[r][kc+7]=w1.w;
    __syncthreads();
    #pragma unroll
    for (int kk=0; kk<BK; kk++){
      float a[4], w[4];
      #pragma unroll
      for (int i=0;i<4;i++) a[i] = As[ty*4+i][kk];
      #pragma unroll
      for (int j=0;j<4;j++) w[j] = Ws[tx*4+j][kk];
      #pragma unroll
      for (int i=0;i<4;i++)
        #pragma unroll
        for (int j=0;j<4;j++) acc[i][j] = fmaf(a[i], w[j], acc[i][j]);
    }
  }
  #pragma unroll
  for (int i=0;i<4;i++){
    int id2 = rid[ty*4+i];
    if (id2 < 0) continue;
    float* dst = ((id2 >> 11) ? gil : gis) + (size_t)(id2 & (TBn-1))*G3;
    #pragma unroll
    for (int j=0;j<4;j++){
      int col = nt*BN + tx*4 + j;
      dst[col] = acc[i][j] + bih[p*G3 + col];
    }
  }
}

// ---------- one recurrence step: gh matvec + GRU + scatter + emit ----------
#define DC 16
#define PB 8
__global__ __launch_bounds__(256) void k_step(int t,
    const float* __restrict__ hin, float* __restrict__ hout,
    const int* __restrict__ qi, const int* __restrict__ qni,
    const float* __restrict__ Whh, const float* __restrict__ bhh,
    const float* __restrict__ gis, const float* __restrict__ gil,
    float* __restrict__ out){
  int p  = blockIdx.x;          // party
  int d0 = blockIdx.y * DC;     // d-chunk base
  int tid = threadIdx.x;
  int wave = tid >> 6, lane = tid & 63;

  __shared__ int   mb[64];
  __shared__ int   msz_s;
  __shared__ float ghs[64][49];            // gh per pair, local rows 0..47 (gate*16+dd)
  __shared__ float part[4][PB][12][17];    // per-wave partials (16 groups of 4 lanes)
  __shared__ float res_s[Bn][DC];
  __shared__ float res_l[Bn][DC];

  if (tid == 0){
    int m = 0;
    for (int b=0;b<Bn;b++) if (qi[t*Bn+b]  == p) mb[m++] = b;        // role 0 (speaker)
    for (int b=0;b<Bn;b++) if (qni[t*Bn+b] == p) mb[m++] = b | 256;  // role 1 (listener)
    msz_s = m;
  }
  __syncthreads();
  int m = msz_s;

  for (int base=0; base<m; base+=PB){
    int nb = m - base; if (nb > PB) nb = PB;
    float hreg[PB][8];
    #pragma unroll
    for (int pb=0; pb<PB; pb++){
      if (pb < nb){
        int b = mb[base+pb] & 255;
        const float4* hp = (const float4*)(hin + ((size_t)b*Pn + p)*Dn + lane*8);
        float4 v0 = hp[0], v1 = hp[1];
        hreg[pb][0]=v0.x; hreg[pb][1]=v0.y; hreg[pb][2]=v0.z; hreg[pb][3]=v0.w;
        hreg[pb][4]=v1.x; hreg[pb][5]=v1.y; hreg[pb][6]=v1.z; hreg[pb][7]=v1.w;
      } else {
        #pragma unroll
        for (int jj=0;jj<8;jj++) hreg[pb][jj]=0.f;
      }
    }
    #pragma unroll 1
    for (int rr=0; rr<12; rr++){
      int lr = wave*12 + rr;                         // 0..47
      int grow = (lr >> 4)*Dn + d0 + (lr & 15);      // gate*512 + d
      const float4* wp = (const float4*)(Whh + ((size_t)p*G3 + grow)*Dn + lane*8);
      float4 w0 = wp[0], w1 = wp[1];
      float wv[8] = {w0.x,w0.y,w0.z,w0.w,w1.x,w1.y,w1.z,w1.w};
      float a[PB];
      #pragma unroll
      for (int pb=0;pb<PB;pb++){
        float acc = 0.f;
        #pragma unroll
        for (int jj=0;jj<8;jj++) acc = fmaf(wv[jj], hreg[pb][jj], acc);
        a[pb] = acc;
      }
      #pragma unroll
      for (int pb=0;pb<PB;pb++){
        a[pb] += __shfl_xor(a[pb], 1);
        a[pb] += __shfl_xor(a[pb], 2);
      }
      if ((lane & 3) == 0){
        int q = lane >> 2;
        #pragma unroll
        for (int pb=0;pb<PB;pb++) part[wave][pb][rr][q] = a[pb];
      }
    }
    #pragma unroll
    for (int pass=0; pass<2; pass++){
      int idx = pass*64 + lane;
      if (idx < PB*12){
        int pb = idx/12, rr = idx%12;
        if (pb < nb){
          float s = 0.f;
          #pragma unroll
          for (int q=0;q<16;q++) s += part[wave][pb][rr][q];
          ghs[base+pb][wave*12+rr] = s;
        }
      }
    }
  }
  __syncthreads();

  // GRU elementwise per (pair, dd)
  for (int e=tid; e<m*DC; e+=256){
    int pi = e >> 4, dd = e & 15;
    int ent = mb[pi]; int b = ent & 255; int role = ent >> 8;
    const float* gi = (role ? gil : gis) + (size_t)(t*Bn + b)*G3;
    int d = d0 + dd;
    float hv  = hin[((size_t)b*Pn + p)*Dn + d];
    float ir  = gi[d], iz = gi[Dn + d], inn = gi[2*Dn + d];
    float hr  = ghs[pi][dd]        + bhh[p*G3 + d];
    float hz  = ghs[pi][DC + dd]   + bhh[p*G3 + Dn + d];
    float hn  = ghs[pi][2*DC + dd] + bhh[p*G3 + 2*Dn + d];
    float rg  = fsigmoid(ir + hr);
    float zg  = fsigmoid(iz + hz);
    float ng  = tanhf(fmaf(rg, hn, inn));
    float hnew = fmaf(zg, hv - ng, ng);   // (1-z)*n + z*h
    if (role) res_l[b][dd] = hnew; else res_s[b][dd] = hnew;
  }
  __syncthreads();

  // state scatter (ping-pong) + output emit
  for (int e=tid; e<Bn*DC; e+=256){
    int b = e >> 4, dd = e & 15;
    int d = d0 + dd;
    int sp = qi[t*Bn+b], lp = qni[t*Bn+b];
    float hv = hin[((size_t)b*Pn + p)*Dn + d];
    float v = hv;
    bool isp = (sp == p), ilp = (lp == p);
    if (isp && ilp)      v = res_s[b][dd] + res_l[b][dd] - hv;
    else if (isp)        v = res_s[b][dd];
    else if (ilp)        v = res_l[b][dd];
    hout[((size_t)b*Pn + p)*Dn + d] = v;
    if (isp) out[((size_t)(t+1)*Bn + b)*Dn + d] = v;
  }
}

extern "C" void kernel_launch(void* const* d_in, const int* in_sizes, int n_in,
                              void* d_out, int out_size, void* d_ws, size_t ws_size,
                              hipStream_t stream){
  const float* U    = (const float*)d_in[0];
  const float* SK   = (const float*)d_in[1];
  const float* NU   = (const float*)d_in[2];
  const float* LK   = (const float*)d_in[3];
  // d_in[4] = A (unused by reference)
  const float* qmask= (const float*)d_in[5];
  const float* Wk   = (const float*)d_in[6];
  const float* bk   = (const float*)d_in[7];
  const float* Wq   = (const float*)d_in[8];
  const float* bq   = (const float*)d_in[9];
  const float* Wp   = (const float*)d_in[10];
  const float* bp   = (const float*)d_in[11];
  const float* Wih  = (const float*)d_in[12];
  const float* Whh  = (const float*)d_in[13];
  const float* bih  = (const float*)d_in[14];
  const float* bhh  = (const float*)d_in[15];
  float* out = (float*)d_out;

  float* w = (float*)d_ws;
  size_t off = 0;
  auto alloc = [&](size_t n){ float* pp = w + off; off += n; return pp; };
  float* kxA  = alloc(2048UL*1024);   // kx0 | kx1
  float* kxB  = alloc(2048UL*1024);   // kx2 | kx3
  float* qxA  = alloc(2048UL*512);    // qx0, later qx1
  float* qxB  = alloc(2048UL*512);    // qx2, later qx3
  float* pkx0 = alloc(2048UL*512);
  float* pkx1 = alloc(2048UL*512);
  float* pkx2 = alloc(2048UL*512);
  float* pkx3 = alloc(2048UL*512);
  float* s0   = alloc(2048UL*512);    // s_0, later s_s
  float* s1   = alloc(2048UL*512);    // s_1, later s_l
  float* gis  = alloc(2048UL*1536);
  float* gil  = alloc(2048UL*1536);
  float* hA   = alloc(32UL*9*512);
  float* hB   = alloc(32UL*9*512);
  int* qi     = (int*)(w + off); off += 2048;
  int* qni    = (int*)(w + off); off += 2048;
  int* counts = (int*)(w + off); off += 16;
  int* lists  = (int*)(w + off); off += 9*4096;
  (void)ws_size; (void)in_sizes; (void)n_in; (void)out_size;

  dim3 blk(256);
  const int DD = 512*512;

  k_prep <<<64, blk, 0, stream>>>(qmask, qi, qni, hA, out, counts);
  k_lists<<<16, blk, 0, stream>>>(qi, qni, counts, lists);

  k_gemm<<<dim3(16,32), blk, 0, stream>>>(SK, 512, Wk,        bk,      kxA, 1024);
  k_gemm<<<dim3(16,32), blk, 0, stream>>>(LK, 512, Wk+2*DD,   bk+1024, kxB, 1024);
  k_gemm<<<dim3(8,32),  blk, 0, stream>>>(U,  512, Wq,        bq,      qxA, 512);
  k_gemm<<<dim3(8,32),  blk, 0, stream>>>(NU, 512, Wq+2*DD,   bq+1024, qxB, 512);
  k_gemm<<<dim3(8,32),  blk, 0, stream>>>(kxA,     1024, Wp,      nullptr, pkx0, 512);
  k_gemm<<<dim3(8,32),  blk, 0, stream>>>(kxA+512, 1024, Wp+DD,   nullptr, pkx1, 512);
  k_gemm<<<dim3(8,32),  blk, 0, stream>>>(kxB,     1024, Wp+2*DD, nullptr, pkx2, 512);
  k_gemm<<<dim3(8,32),  blk, 0, stream>>>(kxB+512, 1024, Wp+3*DD, nullptr, pkx3, 512);

  k_score<<<64, blk, 0, stream>>>(qxA, kxA,     1024, pkx0, bp,      s0);  // s_0
  k_score<<<64, blk, 0, stream>>>(qxB, kxB,     1024, pkx2, bp+1024, s1);  // s_1

  k_gemm<<<dim3(8,32),  blk, 0, stream>>>(s0, 512, Wq+DD,   bq+512,  qxA, 512); // qx1
  k_gemm<<<dim3(8,32),  blk, 0, stream>>>(s1, 512, Wq+3*DD, bq+1536, qxB, 512); // qx3

  k_score<<<64, blk, 0, stream>>>(qxA, kxA+512, 1024, pkx1, bp+512,  s0);  // s_s
  k_score<<<64, blk, 0, stream>>>(qxB, kxB+512, 1024, pkx3, bp+1536, s1);  // s_l

  k_gi<<<dim3(24,64,9), blk, 0, stream>>>(s0, s1, Wih, bih, counts, lists, gis, gil);

  for (int t=0; t<Tn; t++){
    const float* hin = (t & 1) ? hB : hA;
    float* hout      = (t & 1) ? hA : hB;
    k_step<<<dim3(9,32), blk, 0, stream>>>(t, hin, hout, qi, qni, Whh, bhh, gis, gil, out);
  }
}

// Round 2
// 1789.036 us; speedup vs baseline: 1.1503x; 1.1503x over previous
//
#include <hip/hip_runtime.h>
#include <math.h>

#define Tn 64
#define Bn 32
#define Pn 9
#define Dn 512
#define TBn 2048
#define G3 1536

using short8 = __attribute__((ext_vector_type(8))) short;
using f32x4  = __attribute__((ext_vector_type(4))) float;

__device__ __forceinline__ float fsigmoid(float x){ return 1.0f/(1.0f+__expf(-x)); }
__device__ __forceinline__ ushort f2bf(float x){
  unsigned u = __float_as_uint(x);
  return (ushort)((u + 0x7FFFu + ((u>>16)&1u)) >> 16);
}
__device__ __forceinline__ float bf2f(ushort h){
  return __uint_as_float(((unsigned)h)<<16);
}

// ---------- prep: qi/qni argmax, zero h0, zero out row 0, zero counts, lists=-1 ----------
__global__ void k_prep(const float* __restrict__ qmask, int* __restrict__ qi,
                       int* __restrict__ qni, float* __restrict__ h0,
                       float* __restrict__ out, int* __restrict__ counts,
                       int* __restrict__ lists){
  int t = blockIdx.x; int tid = threadIdx.x;
  int gidx = blockIdx.x*256 + tid;
  if (gidx < 16) counts[gidx] = 0;
  for (int i=gidx; i<9*4096; i+=64*256) lists[i] = -1;
  if (tid < Bn){
    int b = tid;
    const float* qm = qmask + ((size_t)t*Bn + b)*Pn;
    int best = 0; float bv = qm[0];
    #pragma unroll
    for (int p=1;p<Pn;p++){ float v=qm[p]; if (v>bv){bv=v;best=p;} }
    qi[t*Bn+b] = best;
    int tn = (t==Tn-1)? t : t+1;
    const float* qmn = qmask + ((size_t)tn*Bn + b)*Pn;
    best = 0; bv = qmn[0];
    #pragma unroll
    for (int p=1;p<Pn;p++){ float v=qmn[p]; if (v>bv){bv=v;best=p;} }
    qni[t*Bn+b] = best;
  }
  for (int i=tid; i<2304; i+=256) h0[t*2304 + i] = 0.f;       // 64*2304 = 32*9*512
  for (int i=tid; i<256;  i+=256) out[t*256 + i] = 0.f;       // 64*256 = 32*512 (row 0)
}

// ---------- build per-party sample lists for the gi gather-GEMM ----------
__global__ void k_lists(const int* __restrict__ qi, const int* __restrict__ qni,
                        int* __restrict__ counts, int* __restrict__ lists){
  int id = blockIdx.x*256 + threadIdx.x;   // 0..4095 ; id = role*2048 + t*32+b
  int role = id >> 11, tb = id & (TBn-1);
  int p = role ? qni[tb] : qi[tb];
  int slot = atomicAdd(&counts[p], 1);
  lists[p*4096 + slot] = id;
}

// ---------- f32 -> [hi(512) | lo(512)] bf16 pack, rows of 512 ----------
__global__ __launch_bounds__(256) void k_pack(const float* __restrict__ X,
                                              ushort* __restrict__ Xpk, int nrows){
  int total = nrows * 128;
  for (int idx = blockIdx.x*256 + threadIdx.x; idx < total; idx += gridDim.x*256){
    int r = idx >> 7, c4 = idx & 127;
    float4 v = ((const float4*)X)[idx];
    ushort h0=f2bf(v.x), h1=f2bf(v.y), h2=f2bf(v.z), h3=f2bf(v.w);
    ushort l0=f2bf(v.x-bf2f(h0)), l1=f2bf(v.y-bf2f(h1)),
           l2=f2bf(v.z-bf2f(h2)), l3=f2bf(v.w-bf2f(h3));
    ushort* base = Xpk + (size_t)r*1024;
    *(ushort4*)(base + c4*4)       = make_ushort4(h0,h1,h2,h3);
    *(ushort4*)(base + 512 + c4*4) = make_ushort4(l0,l1,l2,l3);
  }
}

// ---------- MFMA GEMM: C[M,N] = A[M,512] @ W[N,512]^T (+bias), hi/lo 3-term split ----------
// A,B are bf16 packs; per-term base offsets select hi/lo slices. 64x64x64 tile, 4 waves.
__global__ __launch_bounds__(256) void k_mm(
    const ushort* __restrict__ Apk, int asr, int ahi, int alo,
    const ushort* __restrict__ Bpk, int bsr, int bhi, int blo,
    float* __restrict__ C, int ldc, const float* __restrict__ bias,
    ushort* __restrict__ Cpk)
{
  __shared__ ushort Ash[64*64];
  __shared__ ushort Bsh[64*64];
  int bm = blockIdx.y*64, bn = blockIdx.x*64;
  int tid = threadIdx.x;
  int lane = tid & 63, w = tid >> 6;
  int wm = (w>>1)*32, wn = (w&1)*32;
  f32x4 acc[2][2] = {};
  int r0 = tid >> 3, g0 = tid & 7;
  int r1 = r0 + 32;
  int aoffs[3] = {ahi, ahi, alo};
  int boffs[3] = {bhi, blo, bhi};
  for (int term=0; term<3; ++term){
    const ushort* Ab = Apk + aoffs[term];
    const ushort* Bb = Bpk + boffs[term];
    for (int k0=0; k0<512; k0+=64){
      short8 va0 = *(const short8*)(Ab + (size_t)(bm+r0)*asr + k0 + g0*8);
      short8 va1 = *(const short8*)(Ab + (size_t)(bm+r1)*asr + k0 + g0*8);
      short8 vb0 = *(const short8*)(Bb + (size_t)(bn+r0)*bsr + k0 + g0*8);
      short8 vb1 = *(const short8*)(Bb + (size_t)(bn+r1)*bsr + k0 + g0*8);
      __syncthreads();
      *(short8*)(Ash + r0*64 + ((g0 ^ (r0&7))*8)) = va0;
      *(short8*)(Ash + r1*64 + ((g0 ^ (r1&7))*8)) = va1;
      *(short8*)(Bsh + r0*64 + ((g0 ^ (r0&7))*8)) = vb0;
      *(short8*)(Bsh + r1*64 + ((g0 ^ (r1&7))*8)) = vb1;
      __syncthreads();
      #pragma unroll
      for (int kk=0; kk<2; ++kk){
        int gs = kk*4 + (lane>>4);
        short8 af0, af1, bf0, bf1;
        { int row = wm + (lane&15);      af0 = *(const short8*)(Ash + row*64 + ((gs ^ (row&7))*8)); }
        { int row = wm + 16 + (lane&15); af1 = *(const short8*)(Ash + row*64 + ((gs ^ (row&7))*8)); }
        { int row = wn + (lane&15);      bf0 = *(const short8*)(Bsh + row*64 + ((gs ^ (row&7))*8)); }
        { int row = wn + 16 + (lane&15); bf1 = *(const short8*)(Bsh + row*64 + ((gs ^ (row&7))*8)); }
        acc[0][0] = __builtin_amdgcn_mfma_f32_16x16x32_bf16(af0, bf0, acc[0][0], 0,0,0);
        acc[0][1] = __builtin_amdgcn_mfma_f32_16x16x32_bf16(af0, bf1, acc[0][1], 0,0,0);
        acc[1][0] = __builtin_amdgcn_mfma_f32_16x16x32_bf16(af1, bf0, acc[1][0], 0,0,0);
        acc[1][1] = __builtin_amdgcn_mfma_f32_16x16x32_bf16(af1, bf1, acc[1][1], 0,0,0);
      }
    }
  }
  #pragma unroll
  for (int mi=0; mi<2; ++mi){
    #pragma unroll
    for (int ni=0; ni<2; ++ni){
      #pragma unroll
      for (int i=0;i<4;i++){
        int row = bm + wm + mi*16 + (lane>>4)*4 + i;
        int col = bn + wn + ni*16 + (lane&15);
        float v = acc[mi][ni][i];
        if (bias) v += bias[col];
        if (C) C[(size_t)row*ldc + col] = v;
        if (Cpk){
          ushort h = f2bf(v);
          Cpk[(size_t)row*2*ldc + col] = h;
          Cpk[(size_t)row*2*ldc + ldc + col] = f2bf(v - bf2f(h));
        }
      }
    }
  }
}

// ---------- gather MFMA GEMM (per-party GRU input gates): gi[row] = s[row] @ Wih[p]^T + bih ----------
__global__ __launch_bounds__(256) void k_mm_g(
    const ushort* __restrict__ Spk0, const ushort* __restrict__ Spk1,
    const ushort* __restrict__ Wihpk, const float* __restrict__ bih,
    const int* __restrict__ counts, const int* __restrict__ lists,
    float* __restrict__ gis, float* __restrict__ gil)
{
  int p = blockIdx.z;
  int mt = blockIdx.y;
  if (mt*64 >= counts[p]) return;
  int bn = blockIdx.x*64;
  __shared__ ushort Ash[64*64];
  __shared__ ushort Bsh[64*64];
  __shared__ int rid[64];
  int tid = threadIdx.x;
  int lane = tid & 63, w = tid >> 6;
  int wm = (w>>1)*32, wn = (w&1)*32;
  if (tid < 64) rid[tid] = lists[p*4096 + mt*64 + tid];
  __syncthreads();
  f32x4 acc[2][2] = {};
  int r0 = tid >> 3, g0 = tid & 7;
  int r1 = r0 + 32;
  int id0 = rid[r0], id1 = rid[r1];
  const ushort* As0 = (id0 >= 0) ? (((id0>>11)? Spk1:Spk0) + (size_t)(id0 & (TBn-1))*1024) : nullptr;
  const ushort* As1 = (id1 >= 0) ? (((id1>>11)? Spk1:Spk0) + (size_t)(id1 & (TBn-1))*1024) : nullptr;
  const ushort* Wb  = Wihpk + (size_t)(p*G3 + bn)*1024;
  int aoffs[3] = {0, 0, 512};
  int boffs[3] = {0, 512, 0};
  short8 zz = {0,0,0,0,0,0,0,0};
  for (int term=0; term<3; ++term){
    int ao = aoffs[term], bo = boffs[term];
    for (int k0=0; k0<512; k0+=64){
      short8 va0 = As0 ? *(const short8*)(As0 + ao + k0 + g0*8) : zz;
      short8 va1 = As1 ? *(const short8*)(As1 + ao + k0 + g0*8) : zz;
      short8 vb0 = *(const short8*)(Wb + (size_t)r0*1024 + bo + k0 + g0*8);
      short8 vb1 = *(const short8*)(Wb + (size_t)r1*1024 + bo + k0 + g0*8);
      __syncthreads();
      *(short8*)(Ash + r0*64 + ((g0 ^ (r0&7))*8)) = va0;
      *(short8*)(Ash + r1*64 + ((g0 ^ (r1&7))*8)) = va1;
      *(short8*)(Bsh + r0*64 + ((g0 ^ (r0&7))*8)) = vb0;
      *(short8*)(Bsh + r1*64 + ((g0 ^ (r1&7))*8)) = vb1;
      __syncthreads();
      #pragma unroll
      for (int kk=0; kk<2; ++kk){
        int gs = kk*4 + (lane>>4);
        short8 af0, af1, bf0, bf1;
        { int row = wm + (lane&15);      af0 = *(const short8*)(Ash + row*64 + ((gs ^ (row&7))*8)); }
        { int row = wm + 16 + (lane&15); af1 = *(const short8*)(Ash + row*64 + ((gs ^ (row&7))*8)); }
        { int row = wn + (lane&15);      bf0 = *(const short8*)(Bsh + row*64 + ((gs ^ (row&7))*8)); }
        { int row = wn + 16 + (lane&15); bf1 = *(const short8*)(Bsh + row*64 + ((gs ^ (row&7))*8)); }
        acc[0][0] = __builtin_amdgcn_mfma_f32_16x16x32_bf16(af0, bf0, acc[0][0], 0,0,0);
        acc[0][1] = __builtin_amdgcn_mfma_f32_16x16x32_bf16(af0, bf1, acc[0][1], 0,0,0);
        acc[1][0] = __builtin_amdgcn_mfma_f32_16x16x32_bf16(af1, bf0, acc[1][0], 0,0,0);
        acc[1][1] = __builtin_amdgcn_mfma_f32_16x16x32_bf16(af1, bf1, acc[1][1], 0,0,0);
      }
    }
  }
  #pragma unroll
  for (int mi=0; mi<2; ++mi){
    #pragma unroll
    for (int ni=0; ni<2; ++ni){
      #pragma unroll
      for (int i=0;i<4;i++){
        int lrow = wm + mi*16 + (lane>>4)*4 + i;
        int id = rid[lrow];
        if (id < 0) continue;
        int col = bn + wn + ni*16 + (lane&15);
        float v = acc[mi][ni][i] + bih[p*G3 + col];
        float* dst = ((id>>11) ? gil : gis) + (size_t)(id & (TBn-1))*G3;
        dst[col] = v;
      }
    }
  }
}

// ---------- per-t batch-axis softmax + context scale; k from pack; out packed ----------
__global__ __launch_bounds__(256) void k_score(const float* __restrict__ qx,
      const ushort* __restrict__ khi, const ushort* __restrict__ klo, int ksr,
      const float* __restrict__ pkx, const float* __restrict__ bp,
      ushort* __restrict__ spk){
  int t = blockIdx.x; int tid = threadIdx.x;
  __shared__ float part[256];
  __shared__ float dots[32];
  __shared__ float sc[32];
  int b = tid >> 3, j = tid & 7;
  const float* q = qx + ((size_t)t*Bn + b)*Dn;
  const ushort* kh = khi + ((size_t)t*Bn + b)*ksr;
  const ushort* kl = klo + ((size_t)t*Bn + b)*ksr;
  float s = 0.f;
  for (int d=j; d<Dn; d+=8) s = fmaf(q[d], bf2f(kh[d]) + bf2f(kl[d]), s);
  part[tid] = s;
  __syncthreads();
  if (tid < 32){
    float acc = 0.f;
    #pragma unroll
    for (int jj=0;jj<8;jj++) acc += part[tid*8+jj];
    dots[tid] = acc;
  }
  __syncthreads();
  if (tid < 32){
    float mx = dots[0];
    for (int o=1;o<32;o++) mx = fmaxf(mx, dots[o]);
    sc[tid] = __expf(dots[tid] - mx);
  }
  __syncthreads();
  float myscore = 0.f;
  if (tid < 32){
    float sum = 0.f;
    for (int o=0;o<32;o++) sum += sc[o];
    myscore = sc[tid] / sum;
  }
  __syncthreads();
  if (tid < 32) sc[tid] = myscore;
  __syncthreads();
  for (int idx=tid; idx<Bn*Dn; idx+=256){
    int bb = idx >> 9, d = idx & (Dn-1);
    float v = fmaf(sc[bb], pkx[((size_t)t*Bn+bb)*Dn + d], bp[d]);
    ushort h = f2bf(v);
    size_t o = ((size_t)t*Bn+bb)*1024 + d;
    spk[o] = h;
    spk[o + 512] = f2bf(v - bf2f(h));
  }
}

// ---------- one recurrence step: gh matvec + GRU + scatter + emit ----------
#define DC 16
#define PB 8
__global__ __launch_bounds__(256) void k_step(int t,
    const float* __restrict__ hin, float* __restrict__ hout,
    const int* __restrict__ qi, const int* __restrict__ qni,
    const float* __restrict__ Whh, const float* __restrict__ bhh,
    const float* __restrict__ gis, const float* __restrict__ gil,
    float* __restrict__ out){
  int p  = blockIdx.x;          // party
  int d0 = blockIdx.y * DC;     // d-chunk base
  int tid = threadIdx.x;
  int wave = tid >> 6, lane = tid & 63;

  __shared__ int   mb[64];
  __shared__ int   msz_s;
  __shared__ float ghs[64][49];
  __shared__ float part[4][PB][12][17];
  __shared__ float res_s[Bn][DC];
  __shared__ float res_l[Bn][DC];

  if (tid == 0){
    int m = 0;
    for (int b=0;b<Bn;b++) if (qi[t*Bn+b]  == p) mb[m++] = b;
    for (int b=0;b<Bn;b++) if (qni[t*Bn+b] == p) mb[m++] = b | 256;
    msz_s = m;
  }
  __syncthreads();
  int m = msz_s;

  for (int base=0; base<m; base+=PB){
    int nb = m - base; if (nb > PB) nb = PB;
    float hreg[PB][8];
    #pragma unroll
    for (int pb=0; pb<PB; pb++){
      if (pb < nb){
        int b = mb[base+pb] & 255;
        const float4* hp = (const float4*)(hin + ((size_t)b*Pn + p)*Dn + lane*8);
        float4 v0 = hp[0], v1 = hp[1];
        hreg[pb][0]=v0.x; hreg[pb][1]=v0.y; hreg[pb][2]=v0.z; hreg[pb][3]=v0.w;
        hreg[pb][4]=v1.x; hreg[pb][5]=v1.y; hreg[pb][6]=v1.z; hreg[pb][7]=v1.w;
      } else {
        #pragma unroll
        for (int jj=0;jj<8;jj++) hreg[pb][jj]=0.f;
      }
    }
    #pragma unroll 1
    for (int rr=0; rr<12; rr++){
      int lr = wave*12 + rr;
      int grow = (lr >> 4)*Dn + d0 + (lr & 15);
      const float4* wp = (const float4*)(Whh + ((size_t)p*G3 + grow)*Dn + lane*8);
      float4 w0 = wp[0], w1 = wp[1];
      float wv[8] = {w0.x,w0.y,w0.z,w0.w,w1.x,w1.y,w1.z,w1.w};
      float a[PB];
      #pragma unroll
      for (int pb=0;pb<PB;pb++){
        float acc = 0.f;
        #pragma unroll
        for (int jj=0;jj<8;jj++) acc = fmaf(wv[jj], hreg[pb][jj], acc);
        a[pb] = acc;
      }
      #pragma unroll
      for (int pb=0;pb<PB;pb++){
        a[pb] += __shfl_xor(a[pb], 1);
        a[pb] += __shfl_xor(a[pb], 2);
      }
      if ((lane & 3) == 0){
        int q = lane >> 2;
        #pragma unroll
        for (int pb=0;pb<PB;pb++) part[wave][pb][rr][q] = a[pb];
      }
    }
    #pragma unroll
    for (int pass=0; pass<2; pass++){
      int idx = pass*64 + lane;
      if (idx < PB*12){
        int pb = idx/12, rr = idx%12;
        if (pb < nb){
          float s = 0.f;
          #pragma unroll
          for (int q=0;q<16;q++) s += part[wave][pb][rr][q];
          ghs[base+pb][wave*12+rr] = s;
        }
      }
    }
  }
  __syncthreads();

  for (int e=tid; e<m*DC; e+=256){
    int pi = e >> 4, dd = e & 15;
    int ent = mb[pi]; int b = ent & 255; int role = ent >> 8;
    const float* gi = (role ? gil : gis) + (size_t)(t*Bn + b)*G3;
    int d = d0 + dd;
    float hv  = hin[((size_t)b*Pn + p)*Dn + d];
    float ir  = gi[d], iz = gi[Dn + d], inn = gi[2*Dn + d];
    float hr  = ghs[pi][dd]        + bhh[p*G3 + d];
    float hz  = ghs[pi][DC + dd]   + bhh[p*G3 + Dn + d];
    float hn  = ghs[pi][2*DC + dd] + bhh[p*G3 + 2*Dn + d];
    float rg  = fsigmoid(ir + hr);
    float zg  = fsigmoid(iz + hz);
    float ng  = tanhf(fmaf(rg, hn, inn));
    float hnew = fmaf(zg, hv - ng, ng);
    if (role) res_l[b][dd] = hnew; else res_s[b][dd] = hnew;
  }
  __syncthreads();

  for (int e=tid; e<Bn*DC; e+=256){
    int b = e >> 4, dd = e & 15;
    int d = d0 + dd;
    int sp = qi[t*Bn+b], lp = qni[t*Bn+b];
    float hv = hin[((size_t)b*Pn + p)*Dn + d];
    float v = hv;
    bool isp = (sp == p), ilp = (lp == p);
    if (isp && ilp)      v = res_s[b][dd] + res_l[b][dd] - hv;
    else if (isp)        v = res_s[b][dd];
    else if (ilp)        v = res_l[b][dd];
    hout[((size_t)b*Pn + p)*Dn + d] = v;
    if (isp) out[((size_t)(t+1)*Bn + b)*Dn + d] = v;
  }
}

extern "C" void kernel_launch(void* const* d_in, const int* in_sizes, int n_in,
                              void* d_out, int out_size, void* d_ws, size_t ws_size,
                              hipStream_t stream){
  const float* U    = (const float*)d_in[0];
  const float* SK   = (const float*)d_in[1];
  const float* NU   = (const float*)d_in[2];
  const float* LK   = (const float*)d_in[3];
  const float* qmask= (const float*)d_in[5];
  const float* bk   = (const float*)d_in[7];
  const float* bq   = (const float*)d_in[9];
  const float* bp   = (const float*)d_in[11];
  const float* Wk   = (const float*)d_in[6];
  const float* Wq   = (const float*)d_in[8];
  const float* Wp   = (const float*)d_in[10];
  const float* Wih  = (const float*)d_in[12];
  const float* Whh  = (const float*)d_in[13];
  const float* bih  = (const float*)d_in[14];
  const float* bhh  = (const float*)d_in[15];
  float* out = (float*)d_out;

  char* w = (char*)d_ws;
  size_t off = 0;
  auto alloc = [&](size_t bytes)->void*{ void* p = w + off; off += (bytes + 255) & ~(size_t)255; return p; };
  ushort* SKpk = (ushort*)alloc(2048UL*1024*2);
  ushort* LKpk = (ushort*)alloc(2048UL*1024*2);
  ushort* Upk  = (ushort*)alloc(2048UL*1024*2);
  ushort* NUpk = (ushort*)alloc(2048UL*1024*2);
  ushort* Wkpk = (ushort*)alloc(2048UL*1024*2);
  ushort* Wqpk = (ushort*)alloc(2048UL*1024*2);
  ushort* Wppk = (ushort*)alloc(2048UL*1024*2);
  ushort* Wihpk= (ushort*)alloc(13824UL*1024*2);
  ushort* kxApk= (ushort*)alloc(2048UL*2048*2);
  ushort* kxBpk= (ushort*)alloc(2048UL*2048*2);
  float* qxA   = (float*)alloc(2048UL*512*4);
  float* qxB   = (float*)alloc(2048UL*512*4);
  ushort* s0pk = (ushort*)alloc(2048UL*1024*2);
  ushort* s1pk = (ushort*)alloc(2048UL*1024*2);
  float* gis   = (float*)alloc(2048UL*1536*4);
  float* gil   = (float*)alloc(2048UL*1536*4);
  float* hA    = (float*)alloc(32UL*9*512*4);
  float* hB    = (float*)alloc(32UL*9*512*4);
  int* qi      = (int*)alloc(2048*4);
  int* qni     = (int*)alloc(2048*4);
  int* counts  = (int*)alloc(16*4);
  int* lists   = (int*)alloc(9*4096*4);
  // pkx buffers alias input packs that are dead by the time pkx GEMMs run
  float* pkx0 = (float*)(void*)SKpk;
  float* pkx1 = (float*)(void*)LKpk;
  float* pkx2 = (float*)(void*)Upk;
  float* pkx3 = (float*)(void*)NUpk;
  (void)ws_size; (void)in_sizes; (void)n_in; (void)out_size;

  dim3 blk(256);

  k_prep <<<64, blk, 0, stream>>>(qmask, qi, qni, hA, out, counts, lists);
  k_lists<<<16, blk, 0, stream>>>(qi, qni, counts, lists);

  k_pack<<<512,  blk, 0, stream>>>(SK, SKpk, 2048);
  k_pack<<<512,  blk, 0, stream>>>(LK, LKpk, 2048);
  k_pack<<<512,  blk, 0, stream>>>(U,  Upk,  2048);
  k_pack<<<512,  blk, 0, stream>>>(NU, NUpk, 2048);
  k_pack<<<512,  blk, 0, stream>>>(Wk, Wkpk, 2048);
  k_pack<<<512,  blk, 0, stream>>>(Wq, Wqpk, 2048);
  k_pack<<<512,  blk, 0, stream>>>(Wp, Wppk, 2048);
  k_pack<<<1024, blk, 0, stream>>>(Wih, Wihpk, 13824);

  // batch 1: kx (packed only) and first-stage qx (f32)
  k_mm<<<dim3(16,32), blk, 0, stream>>>(SKpk,1024,0,512, Wkpk,               1024,0,512, nullptr,1024, bk,      kxApk);
  k_mm<<<dim3(16,32), blk, 0, stream>>>(LKpk,1024,0,512, Wkpk+(size_t)1024*1024,1024,0,512, nullptr,1024, bk+1024, kxBpk);
  k_mm<<<dim3(8,32),  blk, 0, stream>>>(Upk, 1024,0,512, Wqpk,               1024,0,512, qxA,512, bq,      nullptr);
  k_mm<<<dim3(8,32),  blk, 0, stream>>>(NUpk,1024,0,512, Wqpk+(size_t)1024*1024,1024,0,512, qxB,512, bq+1024, nullptr);
  // batch 2: pkx_i = kx_i @ Wp_i^T  (f32, no bias; bp added in k_score)
  k_mm<<<dim3(8,32),  blk, 0, stream>>>(kxApk,2048,0,   1024, Wppk,                 1024,0,512, pkx0,512, nullptr, nullptr);
  k_mm<<<dim3(8,32),  blk, 0, stream>>>(kxApk,2048,512, 1536, Wppk+(size_t)512*1024, 1024,0,512, pkx1,512, nullptr, nullptr);
  k_mm<<<dim3(8,32),  blk, 0, stream>>>(kxBpk,2048,0,   1024, Wppk+(size_t)1024*1024,1024,0,512, pkx2,512, nullptr, nullptr);
  k_mm<<<dim3(8,32),  blk, 0, stream>>>(kxBpk,2048,512, 1536, Wppk+(size_t)1536*1024,1024,0,512, pkx3,512, nullptr, nullptr);

  k_score<<<64, blk, 0, stream>>>(qxA, kxApk+0,   kxApk+1024, 2048, pkx0, bp,      s0pk);  // s_0
  k_score<<<64, blk, 0, stream>>>(qxB, kxBpk+0,   kxBpk+1024, 2048, pkx2, bp+1024, s1pk);  // s_1

  k_mm<<<dim3(8,32), blk, 0, stream>>>(s0pk,1024,0,512, Wqpk+(size_t)512*1024, 1024,0,512, qxA,512, bq+512,  nullptr); // qx1
  k_mm<<<dim3(8,32), blk, 0, stream>>>(s1pk,1024,0,512, Wqpk+(size_t)1536*1024,1024,0,512, qxB,512, bq+1536, nullptr); // qx3

  k_score<<<64, blk, 0, stream>>>(qxA, kxApk+512, kxApk+1536, 2048, pkx1, bp+512,  s0pk);  // s_s
  k_score<<<64, blk, 0, stream>>>(qxB, kxBpk+512, kxBpk+1536, 2048, pkx3, bp+1536, s1pk);  // s_l

  k_mm_g<<<dim3(24,64,9), blk, 0, stream>>>(s0pk, s1pk, Wihpk, bih, counts, lists, gis, gil);

  for (int t=0; t<Tn; t++){
    const float* hin = (t & 1) ? hB : hA;
    float* hout      = (t & 1) ? hA : hB;
    k_step<<<dim3(9,32), blk, 0, stream>>>(t, hin, hout, qi, qni, Whh, bhh, gis, gil, out);
  }
}